// Round 13
// baseline (425.146 us; speedup 1.0000x reference)
//
#include <hip/hip_runtime.h>
#include <math.h>

#define Hd 128
#define Wd 128
#define HW 16384

__device__ __forceinline__ float wred(float v) {
  #pragma unroll
  for (int o = 32; o > 0; o >>= 1) v += __shfl_down(v, o, 64);
  return v;
}

// ---- K12 fused: grouped 3x3 key conv (in-register) + e1 + e2-for-stats + c1.
// grid (64 tiles, B=8, s=2), block 256 (16x16 px, 1 px/thread).
// R13: T14 async-stage split on the g-loop. R12 profile: VALUBusy 45%, HBM 15%,
// dur ~98us vs ~45us VALU-busy time -> half the time zero issue; the serialized
// {stage->barrier->compute} per phase is the stall. Now: issue g+1's 11 global
// loads into regs BEFORE computing g from xt[cur], ds_write to xt[cur^1] AFTER
// (vmcnt wait covered by ~1150cy of FMA), 1 barrier/phase. LDS dbuf 27.7KB
// (grid caps at 4 blocks/CU anyway). #pragma unroll on g-loop PRESERVED
// (load-bearing: R5-R10 lesson). Compute order/numerics unchanged from R12.
__global__ __launch_bounds__(256) void k_fused(const float* __restrict__ x,
                                               const float* __restrict__ wkey,
                                               const float* __restrict__ we1,
                                               const float* __restrict__ we2,
                                               const float* __restrict__ be2,
                                               const float* __restrict__ wc1,
                                               float* __restrict__ xv,
                                               float* __restrict__ w1out,
                                               float* __restrict__ spart) {
  __shared__ float xt[2][8][18][24];  // double-buffered halo tiles
  __shared__ float sred2[4][8];
  const int tid = threadIdx.x;
  const int tx = tid & 15, ty = tid >> 4;  // 16x16 tile
  const int b = blockIdx.y, s = blockIdx.z;
  const int h0 = (blockIdx.x >> 3) * 16, w0 = (blockIdx.x & 7) * 16;
  const int p = ((h0 + ty) << 7) + (w0 + tx);

  // issue: 11 strided global loads for group g into regs (in flight across compute)
  auto issue = [&](int g, float* pre) {
    #pragma unroll
    for (int k = 0; k < 11; ++k) {
      const int i = tid + k * 256;
      if (i < 2592) {
        int ch = i / 324, r = i - ch * 324;
        int yy = r / 18, xx = r - yy * 18;
        int gh = h0 + yy - 1, gw = w0 + xx - 1;
        float v = 0.f;
        if (gh >= 0 && gh < Hd && gw >= 0 && gw < Wd)
          v = x[((long)(b * 64 + 32 * s + 8 * g + ch) << 14) + (gh << 7) + gw];
        pre[k] = v;
      }
    }
  };
  // commit: regs -> LDS buffer buf
  auto commit = [&](int buf, const float* pre) {
    #pragma unroll
    for (int k = 0; k < 11; ++k) {
      const int i = tid + k * 256;
      if (i < 2592) {
        int ch = i / 324, r = i - ch * 324;
        int yy = r / 18, xx = r - yy * 18;
        xt[buf][ch][yy][xx] = pre[k];
      }
    }
  };

  float xc[32], kc[32];
  {
    float pre0[11];
    issue(0, pre0);
    commit(0, pre0);
  }
  __syncthreads();
  float preN[11];
  #pragma unroll
  for (int g = 0; g < 4; ++g) {
    if (g < 3) issue(g + 1, preN);  // loads in flight during compute below
    const int cur = g & 1;
    float kacc[8] = {0.f, 0.f, 0.f, 0.f, 0.f, 0.f, 0.f, 0.f};
    const float* wg = wkey + (4 * s + g) * 576;  // 8 oc x 72 weights, wave-uniform
    #pragma unroll
    for (int ich = 0; ich < 8; ++ich) {
      float nb[9];
      #pragma unroll
      for (int rr = 0; rr < 3; ++rr)
        #pragma unroll
        for (int cc = 0; cc < 3; ++cc)
          nb[rr * 3 + cc] = xt[cur][ich][ty + rr][tx + cc];
      xc[8 * g + ich] = nb[4];  // center = own pixel
      #pragma unroll
      for (int oc = 0; oc < 8; ++oc) {
        const float* wr = wg + oc * 72 + ich * 9;
        #pragma unroll
        for (int k9 = 0; k9 < 9; ++k9) kacc[oc] += wr[k9] * nb[k9];
      }
    }
    #pragma unroll
    for (int oc = 0; oc < 8; ++oc) kc[8 * g + oc] = fmaxf(kacc[oc], 0.f);
    if (g < 3) commit((g + 1) & 1, preN);  // waits vmcnt here, covered by compute
    __syncthreads();  // next iteration reads xt[(g+1)&1]
  }
  // value path: grouped 1x1 conv (32->32 per half), channel-major b-major planes
  #pragma unroll 4
  for (int o = 0; o < 32; ++o) {
    const float* wr = wc1 + (32 * s + o) * 32;
    float a = 0.f;
    #pragma unroll
    for (int j = 0; j < 32; ++j) a += wr[j] * xc[j];
    xv[((long)(b * 64 + 32 * s + o) << 14) + p] = a;
  }
  // e1: 64(interleaved x,k) -> 16, ReLU; store b-major adjacent planes (clean)
  float w1a[16];
  #pragma unroll
  for (int o = 0; o < 16; ++o) {
    const float* wr = we1 + (16 * s + o) * 64;
    float a = 0.f;
    #pragma unroll
    for (int j = 0; j < 32; ++j) a += wr[2 * j] * xc[j] + wr[2 * j + 1] * kc[j];
    w1a[o] = fmaxf(a, 0.f);
    w1out[((long)(b * 32 + 16 * s + o) << 14) + p] = w1a[o];
  }
  // e2: 16 -> 36 (+bias), stats ONLY (no stores): per-wave GN sum/sumsq partials
  #pragma unroll
  for (int gl = 0; gl < 4; ++gl) {
    float lgs = 0.f, lgq = 0.f;
    #pragma unroll
    for (int kk = 0; kk < 9; ++kk) {
      const int oc2 = 36 * s + gl * 9 + kk;
      const float* wr = we2 + oc2 * 16;
      float a = be2[oc2];
      #pragma unroll
      for (int ic = 0; ic < 16; ++ic) a += wr[ic] * w1a[ic];
      lgs += a;
      lgq += a * a;
    }
    float r1 = wred(lgs), r2 = wred(lgq);
    if ((tid & 63) == 0) {
      sred2[tid >> 6][2 * gl] = r1;
      sred2[tid >> 6][2 * gl + 1] = r2;
    }
  }
  __syncthreads();
  if (tid < 8) {
    float a = sred2[0][tid] + sred2[1][tid] + sred2[2][tid] + sred2[3][tid];
    spart[blockIdx.x * 128 + b * 16 + s * 8 + tid] = a;
  }
}

// ---- K4: per-pixel local 3x3 conv + CA partials + inline GN-stat finalize.
// grid (8,4,64), 2 vertical px/thread. Wave 0 reduces the 64 spart partials for
// this block's (b,gg). Per-pixel kernels recomputed from w1a (bit-identical e2
// dot order). R12-verified body, unchanged.
// part layout: [row=128][ch=512], row = (by*8+bx)*4 + wave.
__global__ __launch_bounds__(256) void k_local(const float* __restrict__ xv,
                                               const float* __restrict__ w1in,
                                               const float* __restrict__ we2,
                                               const float* __restrict__ be2,
                                               const float* __restrict__ spart,
                                               const float* __restrict__ gnw,
                                               const float* __restrict__ gnb,
                                               float* __restrict__ out,
                                               float* __restrict__ part) {
  __shared__ float xt[8][34][24];
  __shared__ float sminv[2];
  const int tid = threadIdx.x;
  const int tx = tid & 15, ty = tid >> 4;
  const int z = blockIdx.z;
  const int b2 = z >> 2, g = z & 3;
  const int t = b2 & 1, b = b2 >> 1;
  const int gg = 4 * t + g;
  const int h0 = blockIdx.y * 32, w0 = blockIdx.x * 16;
  // stage 8 xv channels (plane b*64 + t*32 + g*8 + ch) with 18x34 halo
  for (int i = tid; i < 8 * 612; i += 256) {
    int ch = i / 612, r = i - ch * 612;
    int yy = r / 18, xx = r - yy * 18;
    int gh = h0 + yy - 1, gw = w0 + xx - 1;
    float v = 0.f;
    if (gh >= 0 && gh < Hd && gw >= 0 && gw < Wd)
      v = xv[((long)(b * 64 + t * 32 + g * 8 + ch) << 14) + (gh << 7) + gw];
    xt[ch][yy][xx] = v;
  }
  // GN stat finalize for this block's group (wave 0): sum 64 tile-partials
  if (tid < 64) {
    const float* sp = spart + tid * 128 + (b * 8 + gg) * 2;
    float sv = sp[0], qv = sp[1];
    #pragma unroll
    for (int o = 32; o > 0; o >>= 1) {
      sv += __shfl_down(sv, o, 64);
      qv += __shfl_down(qv, o, 64);
    }
    if (tid == 0) {
      const float N = 9.f * (float)HW;
      float mm = sv / N;
      float var = qv / N - mm * mm;
      sminv[0] = mm;
      sminv[1] = rsqrtf(var + 1e-5f);
    }
  }
  __syncthreads();
  const float m = sminv[0];
  const float inv = sminv[1];
  const int p0 = ((h0 + 2 * ty) << 7) + (w0 + tx);
  const int p1 = p0 + 128;
  // recompute this group's 9 e2 outputs per pixel from w1a (b-major planes),
  // then fold GN affine. Sequential v0-then-v1 keeps live set small.
  float wn0[9], wn1[9];
  {
    float v[16];
    #pragma unroll
    for (int o = 0; o < 16; ++o)
      v[o] = w1in[((long)(b * 32 + t * 16 + o) << 14) + p0];
    #pragma unroll
    for (int kk = 0; kk < 9; ++kk) {
      const int ch72 = 36 * t + 9 * g + kk;
      const float* wr = we2 + ch72 * 16;
      float a = be2[ch72];
      #pragma unroll
      for (int ic = 0; ic < 16; ++ic) a += wr[ic] * v[ic];
      const float sc = inv * gnw[ch72];
      wn0[kk] = a * sc + (gnb[ch72] - m * sc);
    }
    #pragma unroll
    for (int o = 0; o < 16; ++o)
      v[o] = w1in[((long)(b * 32 + t * 16 + o) << 14) + p1];
    #pragma unroll
    for (int kk = 0; kk < 9; ++kk) {
      const int ch72 = 36 * t + 9 * g + kk;
      const float* wr = we2 + ch72 * 16;
      float a = be2[ch72];
      #pragma unroll
      for (int ic = 0; ic < 16; ++ic) a += wr[ic] * v[ic];
      const float sc = inv * gnw[ch72];
      wn1[kk] = a * sc + (gnb[ch72] - m * sc);
    }
  }
  const int prow = (blockIdx.y * 8 + blockIdx.x) * 4 + (tid >> 6);
  #pragma unroll
  for (int cc = 0; cc < 8; ++cc) {
    float nb[12];
    #pragma unroll
    for (int rr = 0; rr < 4; ++rr)
      #pragma unroll
      for (int ccol = 0; ccol < 3; ++ccol)
        nb[rr * 3 + ccol] = xt[cc][2 * ty + rr][tx + ccol];
    float o0 = 0.f, o1 = 0.f;
    #pragma unroll
    for (int dy = 0; dy < 3; ++dy)
      #pragma unroll
      for (int dx = 0; dx < 3; ++dx) {
        o0 += wn0[dy * 3 + dx] * nb[dy * 3 + dx];
        o1 += wn1[dy * 3 + dx] * nb[(dy + 1) * 3 + dx];
      }
    const int ch512 = b2 * 32 + g * 8 + cc;
    out[((long)ch512 << 14) + p0] = o0;
    out[((long)ch512 << 14) + p1] = o1;
    float os = wred(o0 + o1);
    if ((tid & 63) == 0) part[prow * 512 + ch512] = os;
  }
}

// ---- K5: reduce CA partials + SE MLP. R13: grid(8) -- one block per batch,
// 16 loads/thread instead of a single block doing a serial 128-iter reduce.
__global__ void k_ca(const float* __restrict__ part, const float* __restrict__ du1,
                     const float* __restrict__ du2, float* __restrict__ ys) {
  __shared__ float red[8][64];
  __shared__ float sy[64];
  __shared__ float sy4[4];
  const int b = blockIdx.x;
  const int tid = threadIdx.x;  // 512
  const int c = tid & 63, rc = tid >> 6;
  float acc = 0.f;
  #pragma unroll
  for (int r = rc; r < 128; r += 8) acc += part[r * 512 + b * 64 + c];
  red[rc][c] = acc;
  __syncthreads();
  if (tid < 64) {
    float a = 0.f;
    #pragma unroll
    for (int k = 0; k < 8; ++k) a += red[k][tid];
    sy[tid] = a * (1.f / (float)HW);
  }
  __syncthreads();
  if (tid < 4) {
    float a = 0.f;
    for (int c2 = 0; c2 < 64; ++c2) a += sy[c2] * du1[tid * 64 + c2];
    sy4[tid] = fmaxf(a, 0.f);
  }
  __syncthreads();
  if (tid < 64) {
    float z = 0.f;
    #pragma unroll
    for (int j = 0; j < 4; ++j) z += sy4[j] * du2[tid * 4 + j];
    ys[b * 64 + tid] = 1.f / (1.f + expf(-z));
  }
}

// ---- K6: scale output by channel-attention gate ----
__global__ __launch_bounds__(256) void k_scale(float* __restrict__ out,
                                               const float* __restrict__ ys) {
  const long i4 = (long)blockIdx.x * 256 + threadIdx.x;  // float4 index
  const long e = i4 * 4;
  const int bc = (int)(e >> 14);  // b*64+c
  const float s = ys[bc];
  float4* o = (float4*)out;
  float4 v = o[i4];
  v.x *= s; v.y *= s; v.z *= s; v.w *= s;
  o[i4] = v;
}

extern "C" void kernel_launch(void* const* d_in, const int* in_sizes, int n_in,
                              void* d_out, int out_size, void* d_ws, size_t ws_size,
                              hipStream_t stream) {
  const float* x    = (const float*)d_in[0];
  const float* wkey = (const float*)d_in[1];
  const float* we1  = (const float*)d_in[2];
  const float* we2  = (const float*)d_in[3];
  const float* be2  = (const float*)d_in[4];
  const float* gnw  = (const float*)d_in[5];
  const float* gnb  = (const float*)d_in[6];
  const float* wc1  = (const float*)d_in[7];
  const float* du1  = (const float*)d_in[8];
  const float* du2  = (const float*)d_in[9];
  float* out = (float*)d_out;
  float* ws = (float*)d_ws;

  float* xv   = ws;                    // [b][64 ch][HW] floats (channel-major, b-major)
  float* w1a  = ws + 8388608;          // [b][32 ch][HW] floats (channel-major, b-major)
  float* part = ws + 12582912;         // [128][512] CA partials
  float* spart = part + 65536;         // [64][128] GN partials (disjoint from part)
  float* ys   = spart + 8192;          // 512 floats

  k_fused<<<dim3(64, 8, 2), 256, 0, stream>>>(x, wkey, we1, we2, be2, wc1, xv, w1a, spart);
  k_local<<<dim3(8, 4, 64), 256, 0, stream>>>(xv, w1a, we2, be2, spart, gnw, gnb, out, part);
  k_ca<<<8, 512, 0, stream>>>(part, du1, du2, ys);
  k_scale<<<8192, 256, 0, stream>>>(out, ys);
}

// Round 14
// 222.675 us; speedup vs baseline: 1.9093x; 1.9093x over previous
//
#include <hip/hip_runtime.h>
#include <math.h>

#define Hd 128
#define Wd 128
#define HW 16384

__device__ __forceinline__ float wred(float v) {
  #pragma unroll
  for (int o = 32; o > 0; o >>= 1) v += __shfl_down(v, o, 64);
  return v;
}

// ---- K12 fused: grouped 3x3 key conv (in-register) + e1 + e2-for-stats + c1.
// grid (64 tiles, B=8, s=2), block 256 (16x16 px, 1 px/thread).
// R14 = R12 verbatim (best measured: VGPR 60, ~95us, WRITE byte-ideal 49.2MB).
// R13 lesson: register prefetch (T14) blew VGPR to 172 -> occupancy 11.9% -> 3.5x
// slower. This kernel is grid-TLP-capped (16 waves/CU); blocks/CU >= 4 is sacred.
// #pragma unroll on the g-loop is load-bearing (R5-R10: dropping it = +70% dur).
__global__ __launch_bounds__(256) void k_fused(const float* __restrict__ x,
                                               const float* __restrict__ wkey,
                                               const float* __restrict__ we1,
                                               const float* __restrict__ we2,
                                               const float* __restrict__ be2,
                                               const float* __restrict__ wc1,
                                               float* __restrict__ xv,
                                               float* __restrict__ w1out,
                                               float* __restrict__ spart) {
  __shared__ float xt[8][18][24];
  __shared__ float sred2[4][8];
  const int tid = threadIdx.x;
  const int tx = tid & 15, ty = tid >> 4;  // 16x16 tile
  const int b = blockIdx.y, s = blockIdx.z;
  const int h0 = (blockIdx.x >> 3) * 16, w0 = (blockIdx.x & 7) * 16;
  const int p = ((h0 + ty) << 7) + (w0 + tx);
  float xc[32], kc[32];
  #pragma unroll
  for (int g = 0; g < 4; ++g) {
    // stage 8 channels (32s+8g .. +7) with 18x18 halo, rows padded to 24
    for (int i = tid; i < 8 * 324; i += 256) {
      int ch = i / 324, r = i - ch * 324;
      int yy = r / 18, xx = r - yy * 18;
      int gh = h0 + yy - 1, gw = w0 + xx - 1;
      float v = 0.f;
      if (gh >= 0 && gh < Hd && gw >= 0 && gw < Wd)
        v = x[((long)(b * 64 + 32 * s + 8 * g + ch) << 14) + (gh << 7) + gw];
      xt[ch][yy][xx] = v;
    }
    __syncthreads();
    float kacc[8] = {0.f, 0.f, 0.f, 0.f, 0.f, 0.f, 0.f, 0.f};
    const float* wg = wkey + (4 * s + g) * 576;  // 8 oc x 72 weights, wave-uniform
    #pragma unroll
    for (int ich = 0; ich < 8; ++ich) {
      float nb[9];
      #pragma unroll
      for (int rr = 0; rr < 3; ++rr)
        #pragma unroll
        for (int cc = 0; cc < 3; ++cc)
          nb[rr * 3 + cc] = xt[ich][ty + rr][tx + cc];
      xc[8 * g + ich] = nb[4];  // center = own pixel
      #pragma unroll
      for (int oc = 0; oc < 8; ++oc) {
        const float* wr = wg + oc * 72 + ich * 9;
        #pragma unroll
        for (int k9 = 0; k9 < 9; ++k9) kacc[oc] += wr[k9] * nb[k9];
      }
    }
    #pragma unroll
    for (int oc = 0; oc < 8; ++oc) kc[8 * g + oc] = fmaxf(kacc[oc], 0.f);
    __syncthreads();  // before next group's staging overwrites
  }
  // value path: grouped 1x1 conv (32->32 per half), channel-major b-major planes
  #pragma unroll 4
  for (int o = 0; o < 32; ++o) {
    const float* wr = wc1 + (32 * s + o) * 32;
    float a = 0.f;
    #pragma unroll
    for (int j = 0; j < 32; ++j) a += wr[j] * xc[j];
    xv[((long)(b * 64 + 32 * s + o) << 14) + p] = a;
  }
  // e1: 64(interleaved x,k) -> 16, ReLU; store b-major adjacent planes (clean)
  float w1a[16];
  #pragma unroll
  for (int o = 0; o < 16; ++o) {
    const float* wr = we1 + (16 * s + o) * 64;
    float a = 0.f;
    #pragma unroll
    for (int j = 0; j < 32; ++j) a += wr[2 * j] * xc[j] + wr[2 * j + 1] * kc[j];
    w1a[o] = fmaxf(a, 0.f);
    w1out[((long)(b * 32 + 16 * s + o) << 14) + p] = w1a[o];
  }
  // e2: 16 -> 36 (+bias), stats ONLY (no stores): per-wave GN sum/sumsq partials
  #pragma unroll
  for (int gl = 0; gl < 4; ++gl) {
    float lgs = 0.f, lgq = 0.f;
    #pragma unroll
    for (int kk = 0; kk < 9; ++kk) {
      const int oc2 = 36 * s + gl * 9 + kk;
      const float* wr = we2 + oc2 * 16;
      float a = be2[oc2];
      #pragma unroll
      for (int ic = 0; ic < 16; ++ic) a += wr[ic] * w1a[ic];
      lgs += a;
      lgq += a * a;
    }
    float r1 = wred(lgs), r2 = wred(lgq);
    if ((tid & 63) == 0) {
      sred2[tid >> 6][2 * gl] = r1;
      sred2[tid >> 6][2 * gl + 1] = r2;
    }
  }
  __syncthreads();
  if (tid < 8) {
    float a = sred2[0][tid] + sred2[1][tid] + sred2[2][tid] + sred2[3][tid];
    spart[blockIdx.x * 128 + b * 16 + s * 8 + tid] = a;
  }
}

// ---- K4: per-pixel local 3x3 conv + CA partials + inline GN-stat finalize.
// grid (8,4,64), 2 vertical px/thread. Wave 0 reduces the 64 spart partials for
// this block's (b,gg). Per-pixel kernels recomputed from w1a (bit-identical e2
// dot order). R12-verified body, unchanged.
// part layout: [row=128][ch=512], row = (by*8+bx)*4 + wave.
__global__ __launch_bounds__(256) void k_local(const float* __restrict__ xv,
                                               const float* __restrict__ w1in,
                                               const float* __restrict__ we2,
                                               const float* __restrict__ be2,
                                               const float* __restrict__ spart,
                                               const float* __restrict__ gnw,
                                               const float* __restrict__ gnb,
                                               float* __restrict__ out,
                                               float* __restrict__ part) {
  __shared__ float xt[8][34][24];
  __shared__ float sminv[2];
  const int tid = threadIdx.x;
  const int tx = tid & 15, ty = tid >> 4;
  const int z = blockIdx.z;
  const int b2 = z >> 2, g = z & 3;
  const int t = b2 & 1, b = b2 >> 1;
  const int gg = 4 * t + g;
  const int h0 = blockIdx.y * 32, w0 = blockIdx.x * 16;
  // stage 8 xv channels (plane b*64 + t*32 + g*8 + ch) with 18x34 halo
  for (int i = tid; i < 8 * 612; i += 256) {
    int ch = i / 612, r = i - ch * 612;
    int yy = r / 18, xx = r - yy * 18;
    int gh = h0 + yy - 1, gw = w0 + xx - 1;
    float v = 0.f;
    if (gh >= 0 && gh < Hd && gw >= 0 && gw < Wd)
      v = xv[((long)(b * 64 + t * 32 + g * 8 + ch) << 14) + (gh << 7) + gw];
    xt[ch][yy][xx] = v;
  }
  // GN stat finalize for this block's group (wave 0): sum 64 tile-partials
  if (tid < 64) {
    const float* sp = spart + tid * 128 + (b * 8 + gg) * 2;
    float sv = sp[0], qv = sp[1];
    #pragma unroll
    for (int o = 32; o > 0; o >>= 1) {
      sv += __shfl_down(sv, o, 64);
      qv += __shfl_down(qv, o, 64);
    }
    if (tid == 0) {
      const float N = 9.f * (float)HW;
      float mm = sv / N;
      float var = qv / N - mm * mm;
      sminv[0] = mm;
      sminv[1] = rsqrtf(var + 1e-5f);
    }
  }
  __syncthreads();
  const float m = sminv[0];
  const float inv = sminv[1];
  const int p0 = ((h0 + 2 * ty) << 7) + (w0 + tx);
  const int p1 = p0 + 128;
  // recompute this group's 9 e2 outputs per pixel from w1a (b-major planes),
  // then fold GN affine. Sequential v0-then-v1 keeps live set small.
  float wn0[9], wn1[9];
  {
    float v[16];
    #pragma unroll
    for (int o = 0; o < 16; ++o)
      v[o] = w1in[((long)(b * 32 + t * 16 + o) << 14) + p0];
    #pragma unroll
    for (int kk = 0; kk < 9; ++kk) {
      const int ch72 = 36 * t + 9 * g + kk;
      const float* wr = we2 + ch72 * 16;
      float a = be2[ch72];
      #pragma unroll
      for (int ic = 0; ic < 16; ++ic) a += wr[ic] * v[ic];
      const float sc = inv * gnw[ch72];
      wn0[kk] = a * sc + (gnb[ch72] - m * sc);
    }
    #pragma unroll
    for (int o = 0; o < 16; ++o)
      v[o] = w1in[((long)(b * 32 + t * 16 + o) << 14) + p1];
    #pragma unroll
    for (int kk = 0; kk < 9; ++kk) {
      const int ch72 = 36 * t + 9 * g + kk;
      const float* wr = we2 + ch72 * 16;
      float a = be2[ch72];
      #pragma unroll
      for (int ic = 0; ic < 16; ++ic) a += wr[ic] * v[ic];
      const float sc = inv * gnw[ch72];
      wn1[kk] = a * sc + (gnb[ch72] - m * sc);
    }
  }
  const int prow = (blockIdx.y * 8 + blockIdx.x) * 4 + (tid >> 6);
  #pragma unroll
  for (int cc = 0; cc < 8; ++cc) {
    float nb[12];
    #pragma unroll
    for (int rr = 0; rr < 4; ++rr)
      #pragma unroll
      for (int ccol = 0; ccol < 3; ++ccol)
        nb[rr * 3 + ccol] = xt[cc][2 * ty + rr][tx + ccol];
    float o0 = 0.f, o1 = 0.f;
    #pragma unroll
    for (int dy = 0; dy < 3; ++dy)
      #pragma unroll
      for (int dx = 0; dx < 3; ++dx) {
        o0 += wn0[dy * 3 + dx] * nb[dy * 3 + dx];
        o1 += wn1[dy * 3 + dx] * nb[(dy + 1) * 3 + dx];
      }
    const int ch512 = b2 * 32 + g * 8 + cc;
    out[((long)ch512 << 14) + p0] = o0;
    out[((long)ch512 << 14) + p1] = o1;
    float os = wred(o0 + o1);
    if ((tid & 63) == 0) part[prow * 512 + ch512] = os;
  }
}

// ---- K5: reduce CA partials + SE MLP. grid(8) -- one block per batch,
// 16 loads/thread instead of a single block doing a serial 128-iter reduce.
__global__ void k_ca(const float* __restrict__ part, const float* __restrict__ du1,
                     const float* __restrict__ du2, float* __restrict__ ys) {
  __shared__ float red[8][64];
  __shared__ float sy[64];
  __shared__ float sy4[4];
  const int b = blockIdx.x;
  const int tid = threadIdx.x;  // 512
  const int c = tid & 63, rc = tid >> 6;
  float acc = 0.f;
  #pragma unroll
  for (int r = rc; r < 128; r += 8) acc += part[r * 512 + b * 64 + c];
  red[rc][c] = acc;
  __syncthreads();
  if (tid < 64) {
    float a = 0.f;
    #pragma unroll
    for (int k = 0; k < 8; ++k) a += red[k][tid];
    sy[tid] = a * (1.f / (float)HW);
  }
  __syncthreads();
  if (tid < 4) {
    float a = 0.f;
    for (int c2 = 0; c2 < 64; ++c2) a += sy[c2] * du1[tid * 64 + c2];
    sy4[tid] = fmaxf(a, 0.f);
  }
  __syncthreads();
  if (tid < 64) {
    float z = 0.f;
    #pragma unroll
    for (int j = 0; j < 4; ++j) z += sy4[j] * du2[tid * 4 + j];
    ys[b * 64 + tid] = 1.f / (1.f + expf(-z));
  }
}

// ---- K6: scale output by channel-attention gate ----
__global__ __launch_bounds__(256) void k_scale(float* __restrict__ out,
                                               const float* __restrict__ ys) {
  const long i4 = (long)blockIdx.x * 256 + threadIdx.x;  // float4 index
  const long e = i4 * 4;
  const int bc = (int)(e >> 14);  // b*64+c
  const float s = ys[bc];
  float4* o = (float4*)out;
  float4 v = o[i4];
  v.x *= s; v.y *= s; v.z *= s; v.w *= s;
  o[i4] = v;
}

extern "C" void kernel_launch(void* const* d_in, const int* in_sizes, int n_in,
                              void* d_out, int out_size, void* d_ws, size_t ws_size,
                              hipStream_t stream) {
  const float* x    = (const float*)d_in[0];
  const float* wkey = (const float*)d_in[1];
  const float* we1  = (const float*)d_in[2];
  const float* we2  = (const float*)d_in[3];
  const float* be2  = (const float*)d_in[4];
  const float* gnw  = (const float*)d_in[5];
  const float* gnb  = (const float*)d_in[6];
  const float* wc1  = (const float*)d_in[7];
  const float* du1  = (const float*)d_in[8];
  const float* du2  = (const float*)d_in[9];
  float* out = (float*)d_out;
  float* ws = (float*)d_ws;

  float* xv   = ws;                    // [b][64 ch][HW] floats (channel-major, b-major)
  float* w1a  = ws + 8388608;          // [b][32 ch][HW] floats (channel-major, b-major)
  float* part = ws + 12582912;         // [128][512] CA partials
  float* spart = part + 65536;         // [64][128] GN partials (disjoint from part)
  float* ys   = spart + 8192;          // 512 floats

  k_fused<<<dim3(64, 8, 2), 256, 0, stream>>>(x, wkey, we1, we2, be2, wc1, xv, w1a, spart);
  k_local<<<dim3(8, 4, 64), 256, 0, stream>>>(xv, w1a, we2, be2, spart, gnw, gnb, out, part);
  k_ca<<<8, 512, 0, stream>>>(part, du1, du2, ys);
  k_scale<<<8192, 256, 0, stream>>>(out, ys);
}